// Round 1
// baseline (802.296 us; speedup 1.0000x reference)
//
#include <hip/hip_runtime.h>
#include <hip/hip_bf16.h>
#include <float.h>
#include <math.h>

#define NPTS 500
#define NP12 12
#define NPP  4
#define SLOPE 0.01f

__device__ __forceinline__ float lrelu(float x) { return x > 0.f ? x : SLOPE * x; }

// ---------------------------------------------------------------------------
// K1: KNN. grid=(500,3), block=256.
//   p=0: query=cloud_tar, ref=cloud,     k=12 -> inds
//   p=1: query=cloud_tar, ref=cloud_tar, k=12 -> inds_self2
//   p=2: query=cloud,     ref=cloud_tar, k=4  -> inds_pp
// Only the neighbor SET matters downstream (max/mean/softmax-sum are
// order-invariant), so iterative argmin selection is equivalent to top_k.
// ---------------------------------------------------------------------------
__global__ void knn_kernel(const float* __restrict__ cloud,
                           const float* __restrict__ cloud_tar,
                           int* __restrict__ inds,
                           int* __restrict__ inds_self2,
                           int* __restrict__ inds_pp) {
    const int p = blockIdx.y;
    const int n = blockIdx.x;
    const int tid = threadIdx.x;

    const float* Q; const float* R; int k; int* out;
    if (p == 0)      { Q = cloud_tar; R = cloud;     k = NP12; out = inds; }
    else if (p == 1) { Q = cloud_tar; R = cloud_tar; k = NP12; out = inds_self2; }
    else             { Q = cloud;     R = cloud_tar; k = NPP;  out = inds_pp; }

    __shared__ float dist[512];
    __shared__ float rv[256];
    __shared__ int   ri[256];

    const float qx = Q[n * 3 + 0];
    const float qy = Q[n * 3 + 1];
    const float qz = Q[n * 3 + 2];

    for (int r = tid; r < 512; r += 256) {
        float d = FLT_MAX;
        if (r < NPTS) {
            float dx = qx - R[r * 3 + 0];
            float dy = qy - R[r * 3 + 1];
            float dz = qz - R[r * 3 + 2];
            d = dx * dx + dy * dy + dz * dz;
        }
        dist[r] = d;
    }
    __syncthreads();

    for (int t = 0; t < k; ++t) {
        float bv = dist[tid]; int bi = tid;
        float v2 = dist[tid + 256];
        if (v2 < bv) { bv = v2; bi = tid + 256; }
        rv[tid] = bv; ri[tid] = bi;
        __syncthreads();
        for (int s = 128; s > 0; s >>= 1) {
            if (tid < s) {
                if (rv[tid + s] < rv[tid] ||
                    (rv[tid + s] == rv[tid] && ri[tid + s] < ri[tid])) {
                    rv[tid] = rv[tid + s]; ri[tid] = ri[tid + s];
                }
            }
            __syncthreads();
        }
        if (tid == 0) {
            out[n * k + t] = ri[0];
            dist[ri[0]] = FLT_MAX;
        }
        __syncthreads();
    }
}

// ---------------------------------------------------------------------------
// K2: fused 2-layer 1x1 conv chains. grid=(8,4), block=256.
//   chain 0: pfeat(cloud_tar) -> P_ct   (= cf)
//   chain 1: pfeat(cloud)     -> P_c    (= ctf)
//   chain 2: ifeat(img_tar)   -> F_it   (= ifeat(cur_img))
//   chain 3: ifeat(img)       -> F_ic   (= ifeat(tar_img))
// 64 columns per block; wave handles a contiguous row band -> W indices are
// wave-uniform (scalar loads), LDS reads are lane-consecutive.
// ---------------------------------------------------------------------------
__global__ void featchain_kernel(const float* __restrict__ cloud,
                                 const float* __restrict__ cloud_tar,
                                 const float* __restrict__ img,
                                 const float* __restrict__ img_tar,
                                 const float* __restrict__ Wp1, const float* __restrict__ bp1,
                                 const float* __restrict__ Wp2, const float* __restrict__ bp2,
                                 const float* __restrict__ Wi1, const float* __restrict__ bi1,
                                 const float* __restrict__ Wi2, const float* __restrict__ bi2,
                                 float* __restrict__ P_ct, float* __restrict__ P_c,
                                 float* __restrict__ F_it, float* __restrict__ F_ic) {
    __shared__ float xin[32 * 64];
    __shared__ float mid[64 * 64];

    const int chain = blockIdx.y;
    const int tid = threadIdx.x;
    const int wave = tid >> 6;
    const int lane = tid & 63;
    const int col0 = blockIdx.x * 64;

    const float *src, *W1, *B1, *W2, *B2;
    float* dst;
    int Cin; bool coord;
    switch (chain) {
        case 0: src = cloud_tar; W1 = Wp1; B1 = bp1; W2 = Wp2; B2 = bp2; dst = P_ct; Cin = 3;  coord = true;  break;
        case 1: src = cloud;     W1 = Wp1; B1 = bp1; W2 = Wp2; B2 = bp2; dst = P_c;  Cin = 3;  coord = true;  break;
        case 2: src = img_tar;   W1 = Wi1; B1 = bi1; W2 = Wi2; B2 = bi2; dst = F_it; Cin = 32; coord = false; break;
        default:src = img;       W1 = Wi1; B1 = bi1; W2 = Wi2; B2 = bi2; dst = F_ic; Cin = 32; coord = false; break;
    }

    for (int idx = tid; idx < Cin * 64; idx += 256) {
        int i = idx >> 6;
        int cl = idx & 63;
        int n = col0 + cl;
        float v = 0.f;
        if (n < NPTS) v = coord ? src[n * 3 + i] : src[i * NPTS + n];
        xin[i * 64 + cl] = v;
    }
    __syncthreads();

    for (int m = wave * 16; m < wave * 16 + 16; ++m) {
        float acc = B1[m];
        for (int i = 0; i < Cin; ++i)
            acc += W1[m * Cin + i] * xin[i * 64 + lane];
        mid[m * 64 + lane] = lrelu(acc);
    }
    __syncthreads();

    for (int o = wave * 32; o < wave * 32 + 32; ++o) {
        float acc = B2[o];
        for (int m = 0; m < 64; ++m)
            acc += W2[o * 64 + m] * mid[m * 64 + lane];
        int n = col0 + lane;
        if (n < NPTS) dst[o * NPTS + n] = acc;
    }
}

// ---------------------------------------------------------------------------
// K3: global softmax weights. grid=2, block=1024.
//   p=0: w_ct  from inds       (cloud_tar vs cloud)
//   p=1: w_cc  from inds_self2 (cloud_tar vs cloud_tar)
// softmax over ALL 6000 entries (matches reference's global-softmax quirk).
// ---------------------------------------------------------------------------
__global__ void softmax_w_kernel(const float* __restrict__ cloud,
                                 const float* __restrict__ cloud_tar,
                                 const int* __restrict__ inds,
                                 const int* __restrict__ inds_self2,
                                 float* __restrict__ w_ct,
                                 float* __restrict__ w_cc) {
    const int p = blockIdx.x;
    const int tid = threadIdx.x;
    const int* idxArr = (p == 0) ? inds : inds_self2;
    const float* R    = (p == 0) ? cloud : cloud_tar;
    float* w          = (p == 0) ? w_ct : w_cc;

    __shared__ float red[1024];

    float local = 0.f;
    for (int idx = tid; idx < NPTS * NP12; idx += 1024) {
        int n = idx / NP12;
        int nb = idxArr[idx];
        float dx = cloud_tar[n * 3 + 0] - R[nb * 3 + 0];
        float dy = cloud_tar[n * 3 + 1] - R[nb * 3 + 1];
        float dz = cloud_tar[n * 3 + 2] - R[nb * 3 + 2];
        float e = expf(-sqrtf(dx * dx + dy * dy + dz * dz + 1e-12f));
        w[idx] = e;
        local += e;
    }
    red[tid] = local;
    __syncthreads();
    for (int s = 512; s > 0; s >>= 1) {
        if (tid < s) red[tid] += red[tid + s];
        __syncthreads();
    }
    const float total = red[0];
    for (int idx = tid; idx < NPTS * NP12; idx += 1024) {
        w[idx] = w[idx] / total;
    }
}

// ---------------------------------------------------------------------------
// K4: img_diff / cloud_diff via weighted gather + maxpool-12. 250 blocks x 256.
// ---------------------------------------------------------------------------
__global__ void diff_kernel(const float* __restrict__ F_it,
                            const float* __restrict__ F_ic,
                            const float* __restrict__ P_ct,
                            const float* __restrict__ P_c,
                            const int* __restrict__ inds,
                            const float* __restrict__ w_ct,
                            float* __restrict__ img_diff,
                            float* __restrict__ cloud_diff) {
    int gid = blockIdx.x * 256 + threadIdx.x;
    if (gid >= 128 * NPTS) return;
    int ch = gid / NPTS;
    int n  = gid % NPTS;
    float maxI = -FLT_MAX, maxP = -FLT_MAX;
    for (int j = 0; j < NP12; ++j) {
        int idx = inds[n * NP12 + j];
        float w = w_ct[n * NP12 + j];
        maxI = fmaxf(maxI, F_ic[ch * NPTS + idx] * w);
        maxP = fmaxf(maxP, P_c[ch * NPTS + idx] * w);
    }
    img_diff[gid]   = F_it[gid] - maxI;
    cloud_diff[gid] = P_ct[gid] - maxP;
}

// ---------------------------------------------------------------------------
// K5: spd / sid (self-neighbor weighted gather + maxpool-12). 250 blocks x 256.
// ---------------------------------------------------------------------------
__global__ void sdiff_kernel(const float* __restrict__ img_diff,
                             const float* __restrict__ cloud_diff,
                             const int* __restrict__ inds_self2,
                             const float* __restrict__ w_cc,
                             float* __restrict__ spd,
                             float* __restrict__ sid) {
    int gid = blockIdx.x * 256 + threadIdx.x;
    if (gid >= 128 * NPTS) return;
    int ch = gid / NPTS;
    int n  = gid % NPTS;
    float maxP = -FLT_MAX, maxI = -FLT_MAX;
    for (int j = 0; j < NP12; ++j) {
        int idx = inds_self2[n * NP12 + j];
        float w = w_cc[n * NP12 + j];
        maxP = fmaxf(maxP, cloud_diff[ch * NPTS + idx] * w);
        maxI = fmaxf(maxI, img_diff[ch * NPTS + idx] * w);
    }
    spd[gid] = maxP;
    sid[gid] = maxI;
}

// ---------------------------------------------------------------------------
// Generic broadcast-W GEMM: Y[o,n] = b[o] + sum_k W[o, k] * X[k, n]
// X is the (virtual) concat [X1 (K1 rows); X2 (K2 rows)], all (*, 500).
// block=256 (4 waves); wave handles 8 rows x 64 cols. W rows wave-uniform
// -> scalar loads; X loads lane-consecutive -> coalesced.
// mode: 0 = none, 1 = leaky_relu, 2 = multiply by aux[o*500+n]
// ---------------------------------------------------------------------------
__global__ void gemm_bcast_kernel(const float* __restrict__ W,
                                  const float* __restrict__ Bv,
                                  const float* __restrict__ X1, int K1,
                                  const float* __restrict__ X2, int K2,
                                  float* __restrict__ Y, int Cout,
                                  int mode, const float* __restrict__ aux) {
    const int tid  = threadIdx.x;
    const int wave = tid >> 6;
    const int lane = tid & 63;
    const int n  = blockIdx.x * 64 + lane;
    const int nc = (n < NPTS) ? n : (NPTS - 1);
    const int rowg = blockIdx.y * 4 + wave;
    const int o0 = rowg * 8;
    if (o0 >= Cout) return;
    const int Ktot = K1 + K2;

    float acc[8];
#pragma unroll
    for (int r = 0; r < 8; ++r) acc[r] = Bv[o0 + r];

    for (int k = 0; k < K1; ++k) {
        float xv = X1[k * NPTS + nc];
#pragma unroll
        for (int r = 0; r < 8; ++r)
            acc[r] += W[(o0 + r) * Ktot + k] * xv;
    }
    for (int k = 0; k < K2; ++k) {
        float xv = X2[k * NPTS + nc];
#pragma unroll
        for (int r = 0; r < 8; ++r)
            acc[r] += W[(o0 + r) * Ktot + K1 + k] * xv;
    }

    if (n < NPTS) {
#pragma unroll
        for (int r = 0; r < 8; ++r) {
            float v = acc[r];
            if (mode == 1) v = lrelu(v);
            else if (mode == 2) v *= aux[(o0 + r) * NPTS + n];
            Y[(o0 + r) * NPTS + n] = v;
        }
    }
}

// ---------------------------------------------------------------------------
// K_final: out = current_feat + mean_4( tf[:, inds_pp] ). 313 blocks x 256.
// ---------------------------------------------------------------------------
__global__ void final_kernel(const float* __restrict__ current_feat,
                             const float* __restrict__ tf,
                             const int* __restrict__ inds_pp,
                             float* __restrict__ out) {
    int gid = blockIdx.x * 256 + threadIdx.x;
    if (gid >= 160 * NPTS) return;
    int ch = gid / NPTS;
    int n  = gid % NPTS;
    float s = 0.f;
#pragma unroll
    for (int j = 0; j < NPP; ++j) {
        s += tf[ch * NPTS + inds_pp[n * NPP + j]];
    }
    out[gid] = current_feat[gid] + 0.25f * s;
}

// ---------------------------------------------------------------------------
extern "C" void kernel_launch(void* const* d_in, const int* in_sizes, int n_in,
                              void* d_out, int out_size, void* d_ws, size_t ws_size,
                              hipStream_t stream) {
    const float* img          = (const float*)d_in[0];
    const float* cloud        = (const float*)d_in[1];
    const float* img_tar      = (const float*)d_in[2];
    const float* cloud_tar    = (const float*)d_in[3];
    const float* current_feat = (const float*)d_in[4];
    const float* target_feat  = (const float*)d_in[5];
    const float* W_conv1  = (const float*)d_in[6];
    const float* b_conv1  = (const float*)d_in[7];
    const float* W_conv2  = (const float*)d_in[8];
    const float* b_conv2  = (const float*)d_in[9];
    const float* W_pconv1 = (const float*)d_in[10];
    const float* b_pconv1 = (const float*)d_in[11];
    const float* W_pconv2 = (const float*)d_in[12];
    const float* b_pconv2 = (const float*)d_in[13];
    const float* W_fc1    = (const float*)d_in[14];
    const float* b_fc1    = (const float*)d_in[15];
    const float* W_fc2    = (const float*)d_in[16];
    const float* b_fc2    = (const float*)d_in[17];
    const float* W_fuse2  = (const float*)d_in[18];
    const float* b_fuse2  = (const float*)d_in[19];
    const float* W_pn1    = (const float*)d_in[20];
    const float* b_pn1    = (const float*)d_in[21];
    const float* W_pn2    = (const float*)d_in[22];
    const float* b_pn2    = (const float*)d_in[23];
    const float* W_pn3    = (const float*)d_in[24];
    const float* b_pn3    = (const float*)d_in[25];

    float* ws = (float*)d_ws;
    int*   inds       = (int*)(ws + 0);        // 6000
    int*   inds_self2 = (int*)(ws + 6000);     // 6000
    int*   inds_pp    = (int*)(ws + 12000);    // 2000
    float* w_ct       = ws + 14000;            // 6000
    float* w_cc       = ws + 20000;            // 6000
    float* P_ct       = ws + 26000;            // 64000  (cf)
    float* P_c        = ws + 90000;            // 64000  (ctf)
    float* F_it       = ws + 154000;           // 64000  (ifeat(cur_img))
    float* F_ic       = ws + 218000;           // 64000  (ifeat(tar_img))
    float* img_diff   = ws + 282000;           // 64000
    float* cloud_diff = ws + 346000;           // 64000
    float* spd        = ws + 410000;           // 64000
    float* sid        = ws + 474000;           // 64000
    float* fuse_i     = ws + 538000;           // 32000
    float* fuse_p     = ws + 570000;           // 32000
    float* fuse_t_c   = ws + 602000;           // 80000
    float* x1         = ws + 682000;           // 128000
    float* x2         = ws + 810000;           // 512000
    float* tf         = ws + 1322000;          // 80000
    float* out        = (float*)d_out;

    knn_kernel<<<dim3(NPTS, 3), 256, 0, stream>>>(cloud, cloud_tar, inds, inds_self2, inds_pp);

    featchain_kernel<<<dim3(8, 4), 256, 0, stream>>>(
        cloud, cloud_tar, img, img_tar,
        W_pconv1, b_pconv1, W_pconv2, b_pconv2,
        W_conv1, b_conv1, W_conv2, b_conv2,
        P_ct, P_c, F_it, F_ic);

    softmax_w_kernel<<<2, 1024, 0, stream>>>(cloud, cloud_tar, inds, inds_self2, w_ct, w_cc);

    diff_kernel<<<250, 256, 0, stream>>>(F_it, F_ic, P_ct, P_c, inds, w_ct, img_diff, cloud_diff);

    sdiff_kernel<<<250, 256, 0, stream>>>(img_diff, cloud_diff, inds_self2, w_cc, spd, sid);

    // fuse_i = W_fc1 @ [img_diff; spd] + b_fc1   (64,500)
    gemm_bcast_kernel<<<dim3(8, 2), 256, 0, stream>>>(
        W_fc1, b_fc1, img_diff, 128, spd, 128, fuse_i, 64, 0, nullptr);
    // fuse_p = W_fc2 @ [cloud_diff; sid] + b_fc2 (64,500)
    gemm_bcast_kernel<<<dim3(8, 2), 256, 0, stream>>>(
        W_fc2, b_fc2, cloud_diff, 128, sid, 128, fuse_p, 64, 0, nullptr);
    // fuse_t_c = W_fuse2 @ [fuse_p; fuse_i] + b_fuse2  (160,500)
    gemm_bcast_kernel<<<dim3(8, 5), 256, 0, stream>>>(
        W_fuse2, b_fuse2, fuse_p, 64, fuse_i, 64, fuse_t_c, 160, 0, nullptr);
    // x1 = W_pn1 @ fuse_t_c + b_pn1  (256,500), no activation
    gemm_bcast_kernel<<<dim3(8, 8), 256, 0, stream>>>(
        W_pn1, b_pn1, fuse_t_c, 160, nullptr, 0, x1, 256, 0, nullptr);
    // x2 = lrelu(W_pn2 @ x1 + b_pn2)  (1024,500)
    gemm_bcast_kernel<<<dim3(8, 32), 256, 0, stream>>>(
        W_pn2, b_pn2, x1, 256, nullptr, 0, x2, 1024, 1, nullptr);
    // tf = target_feat * (W_pn3 @ x2 + b_pn3)  (160,500)
    gemm_bcast_kernel<<<dim3(8, 5), 256, 0, stream>>>(
        W_pn3, b_pn3, x2, 1024, nullptr, 0, tf, 160, 2, target_feat);

    final_kernel<<<313, 256, 0, stream>>>(current_feat, tf, inds_pp, out);
}

// Round 2
// 268.355 us; speedup vs baseline: 2.9897x; 2.9897x over previous
//
#include <hip/hip_runtime.h>
#include <hip/hip_bf16.h>
#include <float.h>
#include <math.h>

#define NPTS 500
#define NP12 12
#define NPP  4
#define SLOPE 0.01f

__device__ __forceinline__ float lrelu(float x) { return x > 0.f ? x : SLOPE * x; }

// ---------------------------------------------------------------------------
// K1: KNN, wave-per-query. 1500 queries (3 problems x 500), 375 blocks x 256.
//   p=0: query=cloud_tar, ref=cloud,     k=12 -> inds
//   p=1: query=cloud_tar, ref=cloud_tar, k=12 -> inds_self2
//   p=2: query=cloud,     ref=cloud_tar, k=4  -> inds_pp
// Each wave holds all 500 ref distances in registers (8/lane); iterative
// argmin via shfl_xor butterfly, ties -> lowest index (matches top_k).
// ---------------------------------------------------------------------------
__global__ __launch_bounds__(256) void knn_kernel(
        const float* __restrict__ cloud, const float* __restrict__ cloud_tar,
        int* __restrict__ inds, int* __restrict__ inds_self2, int* __restrict__ inds_pp) {
    const int wid  = blockIdx.x * 4 + (threadIdx.x >> 6);
    const int lane = threadIdx.x & 63;
    if (wid >= 1500) return;
    const int p = wid / NPTS;
    const int n = wid % NPTS;

    const float* Q; const float* R; int k; int* out;
    if (p == 0)      { Q = cloud_tar; R = cloud;     k = NP12; out = inds; }
    else if (p == 1) { Q = cloud_tar; R = cloud_tar; k = NP12; out = inds_self2; }
    else             { Q = cloud;     R = cloud_tar; k = NPP;  out = inds_pp; }

    const float qx = Q[n * 3 + 0];
    const float qy = Q[n * 3 + 1];
    const float qz = Q[n * 3 + 2];

    float d[8];
#pragma unroll
    for (int j = 0; j < 8; ++j) {
        int idx = j * 64 + lane;
        float dd = FLT_MAX;
        if (idx < NPTS) {
            float dx = qx - R[idx * 3 + 0];
            float dy = qy - R[idx * 3 + 1];
            float dz = qz - R[idx * 3 + 2];
            dd = dx * dx + dy * dy + dz * dz;
        }
        d[j] = dd;
    }

    for (int t = 0; t < k; ++t) {
        float bv = d[0]; int bj = 0;
#pragma unroll
        for (int j = 1; j < 8; ++j) {
            if (d[j] < bv) { bv = d[j]; bj = j; }
        }
        int bidx = bj * 64 + lane;
#pragma unroll
        for (int s = 32; s >= 1; s >>= 1) {
            float ov = __shfl_xor(bv, s, 64);
            int   oi = __shfl_xor(bidx, s, 64);
            if (ov < bv || (ov == bv && oi < bidx)) { bv = ov; bidx = oi; }
        }
        if (lane == 0) out[n * k + t] = bidx;
        // invalidate winner (static indexing -> stays in registers)
        bool mine = (lane == (bidx & 63));
        int jj = bidx >> 6;
#pragma unroll
        for (int j = 0; j < 8; ++j) {
            if (mine && jj == j) d[j] = FLT_MAX;
        }
    }
}

// ---------------------------------------------------------------------------
// K2: fused 2-layer 1x1 conv chains. grid=(8,4), block=256.
// wave id via readfirstlane so W reads are provably uniform -> s_loads.
// ---------------------------------------------------------------------------
__global__ __launch_bounds__(256) void featchain_kernel(
        const float* __restrict__ cloud, const float* __restrict__ cloud_tar,
        const float* __restrict__ img, const float* __restrict__ img_tar,
        const float* __restrict__ Wp1, const float* __restrict__ bp1,
        const float* __restrict__ Wp2, const float* __restrict__ bp2,
        const float* __restrict__ Wi1, const float* __restrict__ bi1,
        const float* __restrict__ Wi2, const float* __restrict__ bi2,
        float* __restrict__ P_ct, float* __restrict__ P_c,
        float* __restrict__ F_it, float* __restrict__ F_ic) {
    __shared__ float xin[32 * 64];
    __shared__ float mid[64 * 64];

    const int chain = blockIdx.y;
    const int tid = threadIdx.x;
    const int wave = __builtin_amdgcn_readfirstlane(tid >> 6);
    const int lane = tid & 63;
    const int col0 = blockIdx.x * 64;

    const float *src, *W1, *B1, *W2, *B2;
    float* dst;
    int Cin; bool coord;
    switch (chain) {
        case 0: src = cloud_tar; W1 = Wp1; B1 = bp1; W2 = Wp2; B2 = bp2; dst = P_ct; Cin = 3;  coord = true;  break;
        case 1: src = cloud;     W1 = Wp1; B1 = bp1; W2 = Wp2; B2 = bp2; dst = P_c;  Cin = 3;  coord = true;  break;
        case 2: src = img_tar;   W1 = Wi1; B1 = bi1; W2 = Wi2; B2 = bi2; dst = F_it; Cin = 32; coord = false; break;
        default:src = img;       W1 = Wi1; B1 = bi1; W2 = Wi2; B2 = bi2; dst = F_ic; Cin = 32; coord = false; break;
    }

    for (int idx = tid; idx < Cin * 64; idx += 256) {
        int i = idx >> 6;
        int cl = idx & 63;
        int nn = col0 + cl;
        float v = 0.f;
        if (nn < NPTS) v = coord ? src[nn * 3 + i] : src[i * NPTS + nn];
        xin[i * 64 + cl] = v;
    }
    __syncthreads();

    for (int m = wave * 16; m < wave * 16 + 16; ++m) {
        float acc = B1[m];
        for (int i = 0; i < Cin; ++i)
            acc = fmaf(W1[m * Cin + i], xin[i * 64 + lane], acc);
        mid[m * 64 + lane] = lrelu(acc);
    }
    __syncthreads();

    for (int o = wave * 32; o < wave * 32 + 32; ++o) {
        float acc = B2[o];
#pragma unroll 8
        for (int m = 0; m < 64; ++m)
            acc = fmaf(W2[o * 64 + m], mid[m * 64 + lane], acc);
        int nn = col0 + lane;
        if (nn < NPTS) dst[o * NPTS + nn] = acc;
    }
}

// ---------------------------------------------------------------------------
// K3: softmax numerators + global sum via atomics. grid=(8,2), block=256.
// totals[p] must be zeroed before launch. Normalization happens in
// diff/sdiff (multiply by 1/totals[p]).
// ---------------------------------------------------------------------------
__global__ __launch_bounds__(256) void softmax_w_kernel(
        const float* __restrict__ cloud, const float* __restrict__ cloud_tar,
        const int* __restrict__ inds, const int* __restrict__ inds_self2,
        float* __restrict__ w_ct, float* __restrict__ w_cc,
        float* __restrict__ totals) {
    const int p = blockIdx.y;
    const int tid = threadIdx.x;
    const int* idxArr = (p == 0) ? inds : inds_self2;
    const float* R    = (p == 0) ? cloud : cloud_tar;
    float* w          = (p == 0) ? w_ct : w_cc;

    float local = 0.f;
    for (int idx = blockIdx.x * 256 + tid; idx < NPTS * NP12; idx += 8 * 256) {
        int nn = idx / NP12;
        int nb = idxArr[idx];
        float dx = cloud_tar[nn * 3 + 0] - R[nb * 3 + 0];
        float dy = cloud_tar[nn * 3 + 1] - R[nb * 3 + 1];
        float dz = cloud_tar[nn * 3 + 2] - R[nb * 3 + 2];
        float e = expf(-sqrtf(dx * dx + dy * dy + dz * dz + 1e-12f));
        w[idx] = e;
        local += e;
    }
    // wave reduce then one atomic per wave
#pragma unroll
    for (int s = 32; s >= 1; s >>= 1) local += __shfl_xor(local, s, 64);
    if ((tid & 63) == 0) atomicAdd(&totals[p], local);
}

// ---------------------------------------------------------------------------
// K4: img_diff / cloud_diff via weighted gather + maxpool-12.
// ---------------------------------------------------------------------------
__global__ __launch_bounds__(256) void diff_kernel(
        const float* __restrict__ F_it, const float* __restrict__ F_ic,
        const float* __restrict__ P_ct, const float* __restrict__ P_c,
        const int* __restrict__ inds, const float* __restrict__ w_ct,
        const float* __restrict__ totals,
        float* __restrict__ img_diff, float* __restrict__ cloud_diff) {
    int gid = blockIdx.x * 256 + threadIdx.x;
    if (gid >= 128 * NPTS) return;
    int ch = gid / NPTS;
    int n  = gid % NPTS;
    float inv = 1.0f / totals[0];
    float maxI = -FLT_MAX, maxP = -FLT_MAX;
    for (int j = 0; j < NP12; ++j) {
        int idx = inds[n * NP12 + j];
        float w = w_ct[n * NP12 + j] * inv;
        maxI = fmaxf(maxI, F_ic[ch * NPTS + idx] * w);
        maxP = fmaxf(maxP, P_c[ch * NPTS + idx] * w);
    }
    img_diff[gid]   = F_it[gid] - maxI;
    cloud_diff[gid] = P_ct[gid] - maxP;
}

// ---------------------------------------------------------------------------
// K5: spd / sid (self-neighbor weighted gather + maxpool-12).
// ---------------------------------------------------------------------------
__global__ __launch_bounds__(256) void sdiff_kernel(
        const float* __restrict__ img_diff, const float* __restrict__ cloud_diff,
        const int* __restrict__ inds_self2, const float* __restrict__ w_cc,
        const float* __restrict__ totals,
        float* __restrict__ spd, float* __restrict__ sid) {
    int gid = blockIdx.x * 256 + threadIdx.x;
    if (gid >= 128 * NPTS) return;
    int ch = gid / NPTS;
    int n  = gid % NPTS;
    float inv = 1.0f / totals[1];
    float maxP = -FLT_MAX, maxI = -FLT_MAX;
    for (int j = 0; j < NP12; ++j) {
        int idx = inds_self2[n * NP12 + j];
        float w = w_cc[n * NP12 + j] * inv;
        maxP = fmaxf(maxP, cloud_diff[ch * NPTS + idx] * w);
        maxI = fmaxf(maxI, img_diff[ch * NPTS + idx] * w);
    }
    spd[gid] = maxP;
    sid[gid] = maxI;
}

// ---------------------------------------------------------------------------
// GEMM: Y[o,n] = b[o] + sum_k W[o,k] * X[k,n],  X = concat(X1:K1, X2:K2).
// block=256 (4 waves), wave -> 2 rows x 64 cols; grid=(8, Cout/8).
// K chunked by 32: X chunk staged in LDS with float4 bulk loads (one wait
// per chunk); W addresses wave-uniform (readfirstlane) -> scalar loads.
// K1, K2, Cout must be multiples of 32 / 32 / 8 (all are here).
// mode: 0 none, 1 leaky_relu, 2 multiply by aux[o*NPTS+n]
// NOTE: staging over-reads up to 12 floats past each X row-block end
// (cols 448..511); ws buffers are padded so this never leaves the arena.
// ---------------------------------------------------------------------------
__global__ __launch_bounds__(256) void gemm_lds_kernel(
        const float* __restrict__ W, const float* __restrict__ Bv,
        const float* __restrict__ X1, int K1,
        const float* __restrict__ X2, int K2,
        float* __restrict__ Y, int Cout,
        int mode, const float* __restrict__ aux) {
    __shared__ float Xs[32 * 64];
    const int tid  = threadIdx.x;
    const int wave = __builtin_amdgcn_readfirstlane(tid >> 6);
    const int lane = tid & 63;
    const int col0 = blockIdx.x * 64;
    const int n    = col0 + lane;
    const int r0   = blockIdx.y * 8 + wave * 2;
    const int Ktot = K1 + K2;

    float acc0 = Bv[r0];
    float acc1 = Bv[r0 + 1];

    const int srow = tid >> 3;          // 0..31
    const int scol = (tid & 7) * 8;     // 0,8,..,56

    for (int part = 0; part < 2; ++part) {
        const float* X = part ? X2 : X1;
        const int K    = part ? K2 : K1;
        const int koff = part ? K1 : 0;
        for (int kb = 0; kb < K; kb += 32) {
            __syncthreads();
            {
                const float* src = X + (kb + srow) * NPTS + col0 + scol;
                float4 a = *(const float4*)(src);
                float4 b = *(const float4*)(src + 4);
                float* dsh = &Xs[srow * 64 + scol];
                *(float4*)dsh = a;
                *(float4*)(dsh + 4) = b;
            }
            __syncthreads();
            const float* w0 = &W[(r0)     * Ktot + koff + kb];
            const float* w1 = &W[(r0 + 1) * Ktot + koff + kb];
#pragma unroll
            for (int k = 0; k < 32; ++k) {
                float xv = Xs[k * 64 + lane];
                acc0 = fmaf(w0[k], xv, acc0);
                acc1 = fmaf(w1[k], xv, acc1);
            }
        }
    }

    if (n < NPTS) {
        float v0 = acc0, v1 = acc1;
        if (mode == 1) { v0 = lrelu(v0); v1 = lrelu(v1); }
        else if (mode == 2) {
            v0 *= aux[r0 * NPTS + n];
            v1 *= aux[(r0 + 1) * NPTS + n];
        }
        Y[r0 * NPTS + n]       = v0;
        Y[(r0 + 1) * NPTS + n] = v1;
    }
}

// ---------------------------------------------------------------------------
// K_final: out = current_feat + mean_4( tf[:, inds_pp] ).
// ---------------------------------------------------------------------------
__global__ __launch_bounds__(256) void final_kernel(
        const float* __restrict__ current_feat, const float* __restrict__ tf,
        const int* __restrict__ inds_pp, float* __restrict__ out) {
    int gid = blockIdx.x * 256 + threadIdx.x;
    if (gid >= 160 * NPTS) return;
    int ch = gid / NPTS;
    int n  = gid % NPTS;
    float s = 0.f;
#pragma unroll
    for (int j = 0; j < NPP; ++j) {
        s += tf[ch * NPTS + inds_pp[n * NPP + j]];
    }
    out[gid] = current_feat[gid] + 0.25f * s;
}

// ---------------------------------------------------------------------------
extern "C" void kernel_launch(void* const* d_in, const int* in_sizes, int n_in,
                              void* d_out, int out_size, void* d_ws, size_t ws_size,
                              hipStream_t stream) {
    const float* img          = (const float*)d_in[0];
    const float* cloud        = (const float*)d_in[1];
    const float* img_tar      = (const float*)d_in[2];
    const float* cloud_tar    = (const float*)d_in[3];
    const float* current_feat = (const float*)d_in[4];
    const float* target_feat  = (const float*)d_in[5];
    const float* W_conv1  = (const float*)d_in[6];
    const float* b_conv1  = (const float*)d_in[7];
    const float* W_conv2  = (const float*)d_in[8];
    const float* b_conv2  = (const float*)d_in[9];
    const float* W_pconv1 = (const float*)d_in[10];
    const float* b_pconv1 = (const float*)d_in[11];
    const float* W_pconv2 = (const float*)d_in[12];
    const float* b_pconv2 = (const float*)d_in[13];
    const float* W_fc1    = (const float*)d_in[14];
    const float* b_fc1    = (const float*)d_in[15];
    const float* W_fc2    = (const float*)d_in[16];
    const float* b_fc2    = (const float*)d_in[17];
    const float* W_fuse2  = (const float*)d_in[18];
    const float* b_fuse2  = (const float*)d_in[19];
    const float* W_pn1    = (const float*)d_in[20];
    const float* b_pn1    = (const float*)d_in[21];
    const float* W_pn2    = (const float*)d_in[22];
    const float* b_pn2    = (const float*)d_in[23];
    const float* W_pn3    = (const float*)d_in[24];
    const float* b_pn3    = (const float*)d_in[25];

    // ws arena (floats), each region rounded up + 64-float guard gap so the
    // GEMM staging over-read (<=12 floats) never touches a live buffer.
    float* ws = (float*)d_ws;
    size_t off = 0;
    auto alloc = [&](size_t nfl) { float* p = ws + off; off += ((nfl + 63) & ~size_t(63)) + 64; return p; };
    int*   inds       = (int*)alloc(6000);
    int*   inds_self2 = (int*)alloc(6000);
    int*   inds_pp    = (int*)alloc(2000);
    float* w_ct       = alloc(6000);
    float* w_cc       = alloc(6000);
    float* totals     = alloc(2);
    float* P_ct       = alloc(64000);   // cf
    float* P_c        = alloc(64000);   // ctf
    float* F_it       = alloc(64000);   // ifeat(cur_img)
    float* F_ic       = alloc(64000);   // ifeat(tar_img)
    float* img_diff   = alloc(64000);
    float* cloud_diff = alloc(64000);
    float* spd        = alloc(64000);
    float* sid        = alloc(64000);
    float* fuse_i     = alloc(32000);
    float* fuse_p     = alloc(32000);
    float* fuse_t_c   = alloc(80000);
    float* x1         = alloc(128000);
    float* x2         = alloc(512000);
    float* tf         = alloc(80000);
    float* out        = (float*)d_out;

    hipMemsetAsync(totals, 0, 2 * sizeof(float), stream);

    knn_kernel<<<375, 256, 0, stream>>>(cloud, cloud_tar, inds, inds_self2, inds_pp);

    featchain_kernel<<<dim3(8, 4), 256, 0, stream>>>(
        cloud, cloud_tar, img, img_tar,
        W_pconv1, b_pconv1, W_pconv2, b_pconv2,
        W_conv1, b_conv1, W_conv2, b_conv2,
        P_ct, P_c, F_it, F_ic);

    softmax_w_kernel<<<dim3(8, 2), 256, 0, stream>>>(
        cloud, cloud_tar, inds, inds_self2, w_ct, w_cc, totals);

    diff_kernel<<<250, 256, 0, stream>>>(F_it, F_ic, P_ct, P_c, inds, w_ct, totals,
                                         img_diff, cloud_diff);

    sdiff_kernel<<<250, 256, 0, stream>>>(img_diff, cloud_diff, inds_self2, w_cc, totals,
                                          spd, sid);

    // fuse_i = W_fc1 @ [img_diff; spd] + b_fc1   (64,500)
    gemm_lds_kernel<<<dim3(8, 8), 256, 0, stream>>>(
        W_fc1, b_fc1, img_diff, 128, spd, 128, fuse_i, 64, 0, nullptr);
    // fuse_p = W_fc2 @ [cloud_diff; sid] + b_fc2 (64,500)
    gemm_lds_kernel<<<dim3(8, 8), 256, 0, stream>>>(
        W_fc2, b_fc2, cloud_diff, 128, sid, 128, fuse_p, 64, 0, nullptr);
    // fuse_t_c = W_fuse2 @ [fuse_p; fuse_i] + b_fuse2  (160,500)
    gemm_lds_kernel<<<dim3(8, 20), 256, 0, stream>>>(
        W_fuse2, b_fuse2, fuse_p, 64, fuse_i, 64, fuse_t_c, 160, 0, nullptr);
    // x1 = W_pn1 @ fuse_t_c + b_pn1  (256,500)
    gemm_lds_kernel<<<dim3(8, 32), 256, 0, stream>>>(
        W_pn1, b_pn1, fuse_t_c, 160, nullptr, 0, x1, 256, 0, nullptr);
    // x2 = lrelu(W_pn2 @ x1 + b_pn2)  (1024,500)
    gemm_lds_kernel<<<dim3(8, 128), 256, 0, stream>>>(
        W_pn2, b_pn2, x1, 256, nullptr, 0, x2, 1024, 1, nullptr);
    // tf = target_feat * (W_pn3 @ x2 + b_pn3)  (160,500)
    gemm_lds_kernel<<<dim3(8, 20), 256, 0, stream>>>(
        W_pn3, b_pn3, x2, 1024, nullptr, 0, tf, 160, 2, target_feat);

    final_kernel<<<313, 256, 0, stream>>>(current_feat, tf, inds_pp, out);
}

// Round 4
// 215.041 us; speedup vs baseline: 3.7309x; 1.2479x over previous
//
#include <hip/hip_runtime.h>
#include <hip/hip_bf16.h>
#include <float.h>
#include <math.h>

#define NPTS 500
#define NP12 12
#define NPP  4
#define SLOPE 0.01f

__device__ __forceinline__ float lrelu(float x) { return x > 0.f ? x : SLOPE * x; }

// ---------------------------------------------------------------------------
// K1: KNN, wave-per-query, clouds staged in LDS. 1500 queries, 375 blocks.
//   p=0: query=cloud_tar, ref=cloud,     k=12 -> inds
//   p=1: query=cloud_tar, ref=cloud_tar, k=12 -> inds_self2
//   p=2: query=cloud,     ref=cloud_tar, k=4  -> inds_pp
// ---------------------------------------------------------------------------
__global__ __launch_bounds__(256) void knn_kernel(
        const float* __restrict__ cloud, const float* __restrict__ cloud_tar,
        int* __restrict__ inds, int* __restrict__ inds_self2, int* __restrict__ inds_pp) {
    __shared__ float c_lds[1500];
    __shared__ float ct_lds[1500];
    const int tid = threadIdx.x;
    for (int i = tid; i < 1500; i += 256) {
        c_lds[i]  = cloud[i];
        ct_lds[i] = cloud_tar[i];
    }
    __syncthreads();

    const int wid  = blockIdx.x * 4 + (tid >> 6);
    const int lane = tid & 63;
    if (wid >= 1500) return;
    const int p = wid / NPTS;
    const int n = wid % NPTS;

    const float* Q; const float* R; int k; int* out;
    if (p == 0)      { Q = ct_lds; R = c_lds;  k = NP12; out = inds; }
    else if (p == 1) { Q = ct_lds; R = ct_lds; k = NP12; out = inds_self2; }
    else             { Q = c_lds;  R = ct_lds; k = NPP;  out = inds_pp; }

    const float qx = Q[n * 3 + 0];
    const float qy = Q[n * 3 + 1];
    const float qz = Q[n * 3 + 2];

    float d[8];
#pragma unroll
    for (int j = 0; j < 8; ++j) {
        int idx = j * 64 + lane;
        float dd = FLT_MAX;
        if (idx < NPTS) {
            float dx = qx - R[idx * 3 + 0];
            float dy = qy - R[idx * 3 + 1];
            float dz = qz - R[idx * 3 + 2];
            dd = dx * dx + dy * dy + dz * dz;
        }
        d[j] = dd;
    }

    for (int t = 0; t < k; ++t) {
        float bv = d[0]; int bj = 0;
#pragma unroll
        for (int j = 1; j < 8; ++j) {
            if (d[j] < bv) { bv = d[j]; bj = j; }
        }
        int bidx = bj * 64 + lane;
#pragma unroll
        for (int s = 32; s >= 1; s >>= 1) {
            float ov = __shfl_xor(bv, s, 64);
            int   oi = __shfl_xor(bidx, s, 64);
            if (ov < bv || (ov == bv && oi < bidx)) { bv = ov; bidx = oi; }
        }
        if (lane == 0) out[n * k + t] = bidx;
        bool mine = (lane == (bidx & 63));
        int jj = bidx >> 6;
#pragma unroll
        for (int j = 0; j < 8; ++j) {
            if (mine && jj == j) d[j] = FLT_MAX;
        }
    }
}

// ---------------------------------------------------------------------------
// K2: fused 2-layer 1x1 conv chains, register-blocked. grid=(8,4), block=256.
// Layer1: 16 accumulators/lane, one xin LDS read per input channel.
// Layer2: 4 passes x 8 accumulators, one mid LDS read per m (8-way ILP).
// ---------------------------------------------------------------------------
__global__ __launch_bounds__(256) void featchain_kernel(
        const float* __restrict__ cloud, const float* __restrict__ cloud_tar,
        const float* __restrict__ img, const float* __restrict__ img_tar,
        const float* __restrict__ Wp1, const float* __restrict__ bp1,
        const float* __restrict__ Wp2, const float* __restrict__ bp2,
        const float* __restrict__ Wi1, const float* __restrict__ bi1,
        const float* __restrict__ Wi2, const float* __restrict__ bi2,
        float* __restrict__ P_ct, float* __restrict__ P_c,
        float* __restrict__ F_it, float* __restrict__ F_ic) {
    __shared__ float xin[32 * 64];
    __shared__ float mid[64 * 64];

    const int chain = blockIdx.y;
    const int tid = threadIdx.x;
    const int wave = __builtin_amdgcn_readfirstlane(tid >> 6);
    const int lane = tid & 63;
    const int col0 = blockIdx.x * 64;

    const float *src, *W1, *B1, *W2, *B2;
    float* dst;
    int Cin; bool coord;
    switch (chain) {
        case 0: src = cloud_tar; W1 = Wp1; B1 = bp1; W2 = Wp2; B2 = bp2; dst = P_ct; Cin = 3;  coord = true;  break;
        case 1: src = cloud;     W1 = Wp1; B1 = bp1; W2 = Wp2; B2 = bp2; dst = P_c;  Cin = 3;  coord = true;  break;
        case 2: src = img_tar;   W1 = Wi1; B1 = bi1; W2 = Wi2; B2 = bi2; dst = F_it; Cin = 32; coord = false; break;
        default:src = img;       W1 = Wi1; B1 = bi1; W2 = Wi2; B2 = bi2; dst = F_ic; Cin = 32; coord = false; break;
    }

    for (int idx = tid; idx < Cin * 64; idx += 256) {
        int i = idx >> 6;
        int cl = idx & 63;
        int nn = col0 + cl;
        float v = 0.f;
        if (nn < NPTS) v = coord ? src[nn * 3 + i] : src[i * NPTS + nn];
        xin[i * 64 + cl] = v;
    }
    __syncthreads();

    // layer 1: rows wave*16 .. +15, register-blocked
    {
        const int m0 = wave * 16;
        float accm[16];
#pragma unroll
        for (int r = 0; r < 16; ++r) accm[r] = B1[m0 + r];
        for (int i = 0; i < Cin; ++i) {
            float xv = xin[i * 64 + lane];
#pragma unroll
            for (int r = 0; r < 16; ++r)
                accm[r] = fmaf(W1[(m0 + r) * Cin + i], xv, accm[r]);
        }
#pragma unroll
        for (int r = 0; r < 16; ++r)
            mid[(m0 + r) * 64 + lane] = lrelu(accm[r]);
    }
    __syncthreads();

    // layer 2: 4 passes of 8 outputs, one mid read per m
    const int nn = col0 + lane;
    for (int og = 0; og < 4; ++og) {
        const int o0 = wave * 32 + og * 8;
        float acc[8];
#pragma unroll
        for (int r = 0; r < 8; ++r) acc[r] = B2[o0 + r];
#pragma unroll 16
        for (int m = 0; m < 64; ++m) {
            float xv = mid[m * 64 + lane];
#pragma unroll
            for (int r = 0; r < 8; ++r)
                acc[r] = fmaf(W2[(o0 + r) * 64 + m], xv, acc[r]);
        }
        if (nn < NPTS) {
#pragma unroll
            for (int r = 0; r < 8; ++r)
                dst[(o0 + r) * NPTS + nn] = acc[r];
        }
    }
}

// ---------------------------------------------------------------------------
// K3: softmax numerators + direct total write. grid=2 (p), block=1024.
// ---------------------------------------------------------------------------
__global__ __launch_bounds__(1024) void softmax_w_kernel(
        const float* __restrict__ cloud, const float* __restrict__ cloud_tar,
        const int* __restrict__ inds, const int* __restrict__ inds_self2,
        float* __restrict__ w_ct, float* __restrict__ w_cc,
        float* __restrict__ totals) {
    const int p = blockIdx.x;
    const int tid = threadIdx.x;
    const int* idxArr = (p == 0) ? inds : inds_self2;
    const float* R    = (p == 0) ? cloud : cloud_tar;
    float* w          = (p == 0) ? w_ct : w_cc;

    __shared__ float red[1024];
    float local = 0.f;
    for (int idx = tid; idx < NPTS * NP12; idx += 1024) {
        int nn = idx / NP12;
        int nb = idxArr[idx];
        float dx = cloud_tar[nn * 3 + 0] - R[nb * 3 + 0];
        float dy = cloud_tar[nn * 3 + 1] - R[nb * 3 + 1];
        float dz = cloud_tar[nn * 3 + 2] - R[nb * 3 + 2];
        float e = expf(-sqrtf(dx * dx + dy * dy + dz * dz + 1e-12f));
        w[idx] = e;
        local += e;
    }
    red[tid] = local;
    __syncthreads();
    for (int s = 512; s > 0; s >>= 1) {
        if (tid < s) red[tid] += red[tid + s];
        __syncthreads();
    }
    if (tid == 0) totals[p] = red[0];
}

// ---------------------------------------------------------------------------
// K4: img_diff / cloud_diff via weighted gather + maxpool-12 (full unroll).
// ---------------------------------------------------------------------------
__global__ __launch_bounds__(256) void diff_kernel(
        const float* __restrict__ F_it, const float* __restrict__ F_ic,
        const float* __restrict__ P_ct, const float* __restrict__ P_c,
        const int* __restrict__ inds, const float* __restrict__ w_ct,
        const float* __restrict__ totals,
        float* __restrict__ img_diff, float* __restrict__ cloud_diff) {
    int gid = blockIdx.x * 256 + threadIdx.x;
    if (gid >= 128 * NPTS) return;
    int ch = gid / NPTS;
    int n  = gid % NPTS;
    float inv = 1.0f / totals[0];
    int   idxv[NP12];
    float wv[NP12];
#pragma unroll
    for (int j = 0; j < NP12; ++j) {
        idxv[j] = inds[n * NP12 + j];
        wv[j]   = w_ct[n * NP12 + j] * inv;
    }
    float maxI = -FLT_MAX, maxP = -FLT_MAX;
#pragma unroll
    for (int j = 0; j < NP12; ++j) {
        maxI = fmaxf(maxI, F_ic[ch * NPTS + idxv[j]] * wv[j]);
        maxP = fmaxf(maxP, P_c[ch * NPTS + idxv[j]] * wv[j]);
    }
    img_diff[gid]   = F_it[gid] - maxI;
    cloud_diff[gid] = P_ct[gid] - maxP;
}

// ---------------------------------------------------------------------------
// K5: spd / sid (self-neighbor weighted gather + maxpool-12, full unroll).
// ---------------------------------------------------------------------------
__global__ __launch_bounds__(256) void sdiff_kernel(
        const float* __restrict__ img_diff, const float* __restrict__ cloud_diff,
        const int* __restrict__ inds_self2, const float* __restrict__ w_cc,
        const float* __restrict__ totals,
        float* __restrict__ spd, float* __restrict__ sid) {
    int gid = blockIdx.x * 256 + threadIdx.x;
    if (gid >= 128 * NPTS) return;
    int ch = gid / NPTS;
    int n  = gid % NPTS;
    float inv = 1.0f / totals[1];
    int   idxv[NP12];
    float wv[NP12];
#pragma unroll
    for (int j = 0; j < NP12; ++j) {
        idxv[j] = inds_self2[n * NP12 + j];
        wv[j]   = w_cc[n * NP12 + j] * inv;
    }
    float maxP = -FLT_MAX, maxI = -FLT_MAX;
#pragma unroll
    for (int j = 0; j < NP12; ++j) {
        maxP = fmaxf(maxP, cloud_diff[ch * NPTS + idxv[j]] * wv[j]);
        maxI = fmaxf(maxI, img_diff[ch * NPTS + idxv[j]] * wv[j]);
    }
    spd[gid] = maxP;
    sid[gid] = maxI;
}

// ---------------------------------------------------------------------------
// GEMM core: Y[r,n] = bias[r] + sum_k W[r*ldW + kOffW + k] * X[k,n],
// X = virtual concat(X1:K1 rows, X2:K2 rows), all (*,500) row-major.
// wave -> 2 rows x 64 cols; K chunked by 32 staged in LDS; register
// double-buffer: next chunk's global loads issue before current compute.
// No lambdas here: a ref-capturing lambda in this inlined device helper
// segfaulted the ROCm 7.2 clang frontend (round 3).
// Staging over-reads <=12 floats past a row end -> ws guard gaps cover it.
// ---------------------------------------------------------------------------
__device__ __forceinline__ const float* gemm_src(
        const float* __restrict__ X1, int K1, const float* __restrict__ X2,
        int k, int coloff) {
    if (k < K1) return X1 + (size_t)k * NPTS + coloff;
    return X2 + (size_t)(k - K1) * NPTS + coloff;
}

__device__ __forceinline__ void gemm_dev(
        const float* __restrict__ W, int ldW, int kOffW,
        const float* __restrict__ Bv,
        const float* __restrict__ X1, int K1,
        const float* __restrict__ X2, int K2,
        float* __restrict__ Y, int r0, int col0,
        int mode, const float* __restrict__ aux, float* Xs) {
    const int tid  = threadIdx.x;
    const int lane = tid & 63;
    const int n    = col0 + lane;
    const int srow = tid >> 3;          // 0..31
    const int scol = (tid & 7) * 8;     // 0,8,..,56
    const int coloff = col0 + scol;

    float acc0 = Bv ? Bv[r0]     : 0.f;
    float acc1 = Bv ? Bv[r0 + 1] : 0.f;

    const int nchunks = (K1 + K2) >> 5;

    const float* s = gemm_src(X1, K1, X2, srow, coloff);
    float4 ra = *(const float4*)s;
    float4 rb = *(const float4*)(s + 4);

    for (int c = 0; c < nchunks; ++c) {
        __syncthreads();
        float* dsh = &Xs[srow * 64 + scol];
        *(float4*)dsh       = ra;
        *(float4*)(dsh + 4) = rb;
        if (c + 1 < nchunks) {
            const float* sn = gemm_src(X1, K1, X2, (c + 1) * 32 + srow, coloff);
            ra = *(const float4*)sn;
            rb = *(const float4*)(sn + 4);
        }
        __syncthreads();
        const float* w0 = &W[(size_t)r0 * ldW + kOffW + c * 32];
        const float* w1 = w0 + ldW;
#pragma unroll
        for (int k = 0; k < 32; ++k) {
            float xv = Xs[k * 64 + lane];
            acc0 = fmaf(w0[k], xv, acc0);
            acc1 = fmaf(w1[k], xv, acc1);
        }
    }

    if (n < NPTS) {
        float v0 = acc0, v1 = acc1;
        if (mode == 1) { v0 = lrelu(v0); v1 = lrelu(v1); }
        else if (mode == 2) {
            v0 *= aux[r0 * NPTS + n];
            v1 *= aux[(r0 + 1) * NPTS + n];
        }
        Y[r0 * NPTS + n]       = v0;
        Y[(r0 + 1) * NPTS + n] = v1;
    }
}

__global__ __launch_bounds__(256) void gemm_single_kernel(
        const float* __restrict__ W, const float* __restrict__ Bv,
        const float* __restrict__ X1, int K1,
        const float* __restrict__ X2, int K2,
        float* __restrict__ Y, int mode, const float* __restrict__ aux) {
    __shared__ float Xs[32 * 64];
    const int wave = __builtin_amdgcn_readfirstlane(threadIdx.x >> 6);
    gemm_dev(W, K1 + K2, 0, Bv, X1, K1, X2, K2, Y,
             blockIdx.y * 8 + wave * 2, blockIdx.x * 64, mode, aux, Xs);
}

// fc1 + fc2 in one dispatch: grid=(8,16); y<8 -> set A, else set B.
__global__ __launch_bounds__(256) void gemm_pair_kernel(
        const float* __restrict__ Wa, const float* __restrict__ Ba,
        const float* __restrict__ Xa1, const float* __restrict__ Xa2,
        float* __restrict__ Ya,
        const float* __restrict__ Wb, const float* __restrict__ Bb,
        const float* __restrict__ Xb1, const float* __restrict__ Xb2,
        float* __restrict__ Yb) {
    __shared__ float Xs[32 * 64];
    const int wave = __builtin_amdgcn_readfirstlane(threadIdx.x >> 6);
    const int r0 = (blockIdx.y & 7) * 8 + wave * 2;
    if (blockIdx.y < 8)
        gemm_dev(Wa, 256, 0, Ba, Xa1, 128, Xa2, 128, Ya, r0, blockIdx.x * 64, 0, nullptr, Xs);
    else
        gemm_dev(Wb, 256, 0, Bb, Xb1, 128, Xb2, 128, Yb, r0, blockIdx.x * 64, 0, nullptr, Xs);
}

// pn3 split-K: grid=(8,20,4); part p handles k in [p*256,(p+1)*256),
// writes partial (no bias) to part + p*80000.
__global__ __launch_bounds__(256) void gemm_splitk_kernel(
        const float* __restrict__ W, const float* __restrict__ X,
        float* __restrict__ part) {
    __shared__ float Xs[32 * 64];
    const int wave = __builtin_amdgcn_readfirstlane(threadIdx.x >> 6);
    const int p = blockIdx.z;
    gemm_dev(W, 1024, p * 256, nullptr,
             X + (size_t)p * 256 * NPTS, 256, nullptr, 0,
             part + (size_t)p * 80000,
             blockIdx.y * 8 + wave * 2, blockIdx.x * 64, 0, nullptr, Xs);
}

// ---------------------------------------------------------------------------
// K_final (fused pn3-combine): tf[ch,m] = target_feat[ch,m] *
//   (b_pn3[ch] + sum_p part[p][ch,m]);  out = current_feat + mean_4 gather(tf).
// ---------------------------------------------------------------------------
__global__ __launch_bounds__(256) void final_kernel(
        const float* __restrict__ current_feat, const float* __restrict__ target_feat,
        const float* __restrict__ part, const float* __restrict__ b_pn3,
        const int* __restrict__ inds_pp, float* __restrict__ out) {
    int gid = blockIdx.x * 256 + threadIdx.x;
    if (gid >= 160 * NPTS) return;
    int ch = gid / NPTS;
    int n  = gid % NPTS;
    float bias = b_pn3[ch];
    int idxv[NPP];
#pragma unroll
    for (int j = 0; j < NPP; ++j) idxv[j] = inds_pp[n * NPP + j];
    float s = 0.f;
#pragma unroll
    for (int j = 0; j < NPP; ++j) {
        int m = ch * NPTS + idxv[j];
        float v = bias + part[m] + part[80000 + m] + part[160000 + m] + part[240000 + m];
        s += target_feat[m] * v;
    }
    out[gid] = current_feat[gid] + 0.25f * s;
}

// ---------------------------------------------------------------------------
extern "C" void kernel_launch(void* const* d_in, const int* in_sizes, int n_in,
                              void* d_out, int out_size, void* d_ws, size_t ws_size,
                              hipStream_t stream) {
    const float* img          = (const float*)d_in[0];
    const float* cloud        = (const float*)d_in[1];
    const float* img_tar      = (const float*)d_in[2];
    const float* cloud_tar    = (const float*)d_in[3];
    const float* current_feat = (const float*)d_in[4];
    const float* target_feat  = (const float*)d_in[5];
    const float* W_conv1  = (const float*)d_in[6];
    const float* b_conv1  = (const float*)d_in[7];
    const float* W_conv2  = (const float*)d_in[8];
    const float* b_conv2  = (const float*)d_in[9];
    const float* W_pconv1 = (const float*)d_in[10];
    const float* b_pconv1 = (const float*)d_in[11];
    const float* W_pconv2 = (const float*)d_in[12];
    const float* b_pconv2 = (const float*)d_in[13];
    const float* W_fc1    = (const float*)d_in[14];
    const float* b_fc1    = (const float*)d_in[15];
    const float* W_fc2    = (const float*)d_in[16];
    const float* b_fc2    = (const float*)d_in[17];
    const float* W_fuse2  = (const float*)d_in[18];
    const float* b_fuse2  = (const float*)d_in[19];
    const float* W_pn1    = (const float*)d_in[20];
    const float* b_pn1    = (const float*)d_in[21];
    const float* W_pn2    = (const float*)d_in[22];
    const float* b_pn2    = (const float*)d_in[23];
    const float* W_pn3    = (const float*)d_in[24];
    const float* b_pn3    = (const float*)d_in[25];

    // ws arena (floats); every region gets a 64-float guard gap so GEMM
    // staging over-reads (<=12 floats) stay inside the arena.
    float* ws = (float*)d_ws;
    size_t off = 0;
    auto alloc = [&](size_t nfl) { float* p = ws + off; off += ((nfl + 63) & ~size_t(63)) + 64; return p; };
    int*   inds       = (int*)alloc(6000);
    int*   inds_self2 = (int*)alloc(6000);
    int*   inds_pp    = (int*)alloc(2000);
    float* w_ct       = alloc(6000);
    float* w_cc       = alloc(6000);
    float* totals     = alloc(2);
    float* P_ct       = alloc(64000);   // cf
    float* P_c        = alloc(64000);   // ctf
    float* F_it       = alloc(64000);   // ifeat(cur_img)
    float* F_ic       = alloc(64000);   // ifeat(tar_img)
    float* img_diff   = alloc(64000);
    float* cloud_diff = alloc(64000);
    float* spd        = alloc(64000);
    float* sid        = alloc(64000);
    float* fuse_i     = alloc(32000);
    float* fuse_p     = alloc(32000);
    float* fuse_t_c   = alloc(80000);
    float* x1         = alloc(128000);
    float* x2         = alloc(512000);
    float* out        = (float*)d_out;

    // pn3 partials (4 x 80000) alias the img_diff..fuse_p span (all dead
    // once fuse2 has run; pn3 launches after pn1/pn2).
    float* part = img_diff;

    knn_kernel<<<375, 256, 0, stream>>>(cloud, cloud_tar, inds, inds_self2, inds_pp);

    featchain_kernel<<<dim3(8, 4), 256, 0, stream>>>(
        cloud, cloud_tar, img, img_tar,
        W_pconv1, b_pconv1, W_pconv2, b_pconv2,
        W_conv1, b_conv1, W_conv2, b_conv2,
        P_ct, P_c, F_it, F_ic);

    softmax_w_kernel<<<2, 1024, 0, stream>>>(
        cloud, cloud_tar, inds, inds_self2, w_ct, w_cc, totals);

    diff_kernel<<<250, 256, 0, stream>>>(F_it, F_ic, P_ct, P_c, inds, w_ct, totals,
                                         img_diff, cloud_diff);

    sdiff_kernel<<<250, 256, 0, stream>>>(img_diff, cloud_diff, inds_self2, w_cc, totals,
                                          spd, sid);

    // fc1: fuse_i = W_fc1 @ [img_diff; spd] + b_fc1   (64,500)
    // fc2: fuse_p = W_fc2 @ [cloud_diff; sid] + b_fc2 (64,500)
    gemm_pair_kernel<<<dim3(8, 16), 256, 0, stream>>>(
        W_fc1, b_fc1, img_diff, spd, fuse_i,
        W_fc2, b_fc2, cloud_diff, sid, fuse_p);

    // fuse_t_c = W_fuse2 @ [fuse_p; fuse_i] + b_fuse2  (160,500)
    gemm_single_kernel<<<dim3(8, 20), 256, 0, stream>>>(
        W_fuse2, b_fuse2, fuse_p, 64, fuse_i, 64, fuse_t_c, 0, nullptr);
    // x1 = W_pn1 @ fuse_t_c + b_pn1  (256,500)
    gemm_single_kernel<<<dim3(8, 32), 256, 0, stream>>>(
        W_pn1, b_pn1, fuse_t_c, 160, nullptr, 0, x1, 0, nullptr);
    // x2 = lrelu(W_pn2 @ x1 + b_pn2)  (1024,500)
    gemm_single_kernel<<<dim3(8, 128), 256, 0, stream>>>(
        W_pn2, b_pn2, x1, 256, nullptr, 0, x2, 1, nullptr);
    // pn3 partials: part[p] = W_pn3[:, p*256:(p+1)*256] @ x2[p*256:...]  (160,500)
    gemm_splitk_kernel<<<dim3(8, 20, 4), 256, 0, stream>>>(W_pn3, x2, part);

    // out = current_feat + mean_4( target_feat*(sum part + b_pn3) gathered )
    final_kernel<<<313, 256, 0, stream>>>(current_feat, target_feat, part, b_pn3,
                                          inds_pp, out);
}